// Round 3
// baseline (504.097 us; speedup 1.0000x reference)
//
#include <hip/hip_runtime.h>
#include <stdint.h>

// Problem constants
#define BB    64
#define CC    100
#define NBPER 150
#define FEAT  2052
#define KP    2112      // FEAT padded to 33*64 for BK=64 MFMA loop
#define NOUT  2048
#define MR    6400      // BB*CC rows of x / support

typedef __attribute__((ext_vector_type(8))) short   short8;
typedef __attribute__((ext_vector_type(4))) float   floatx4;

__device__ __forceinline__ unsigned short f2bf(float f) {
  unsigned int u = __float_as_uint(f);
  u += 0x7FFFu + ((u >> 16) & 1u);   // RNE
  return (unsigned short)(u >> 16);
}

// async global->LDS, 16B per lane. LDS dest is wave-uniform base; HW does base + lane*16.
__device__ __forceinline__ void async16(const void* g, void* l) {
  __builtin_amdgcn_global_load_lds((__attribute__((address_space(1))) void*)(g),
                                   (__attribute__((address_space(3))) void*)(l),
                                   16, 0, 0);
}

// ---------------------------------------------------------------------------
// K0: gc_w [2052][2048] fp32  ->  gcwT [2048][2112] bf16 (K-major, zero-padded)
// ---------------------------------------------------------------------------
__global__ __launch_bounds__(256) void k_transpose(const float* __restrict__ gcw,
                                                   unsigned short* __restrict__ gcwT) {
  __shared__ float tile[32][33];
  const int ko = blockIdx.x;  // 0..65
  const int oo = blockIdx.y;  // 0..63
  const int tx = threadIdx.x, ty = threadIdx.y;
#pragma unroll
  for (int i = 0; i < 4; ++i) {
    const int k = ko * 32 + ty + i * 8;
    const int o = oo * 32 + tx;
    tile[ty + i * 8][tx] = (k < FEAT) ? gcw[(size_t)k * NOUT + o] : 0.f;
  }
  __syncthreads();
#pragma unroll
  for (int i = 0; i < 4; ++i) {
    const int o = oo * 32 + ty + i * 8;
    const int k = ko * 32 + tx;
    gcwT[(size_t)o * KP + k] = f2bf(tile[tx][ty + i * 8]);
  }
}

// ---------------------------------------------------------------------------
// KB: bucket (fused) + x[b,c,d] = lin_b + sum_slot lin_w[slot]*full[box][d] -> bf16
// ---------------------------------------------------------------------------
__global__ __launch_bounds__(256) void k_buildx(const float* __restrict__ imgf,
                                                const float* __restrict__ bbox,
                                                const float* __restrict__ lw,
                                                const float* __restrict__ lb,
                                                const int* __restrict__ labels,
                                                unsigned short* __restrict__ xbf) {
  __shared__ int lab[NBPER];
  __shared__ int sidx[3];
  const int c = blockIdx.x, b = blockIdx.y;
  const int tid = threadIdx.x;
  if (tid < NBPER) lab[tid] = labels[b * NBPER + tid];
  __syncthreads();
  if (tid == 0) {
    int cnt = 0; sidx[0] = -1; sidx[1] = -1; sidx[2] = -1;
    for (int i = 0; i < NBPER; ++i)
      if (lab[i] == c + 1 && cnt < 3) { sidx[cnt] = b * NBPER + i; ++cnt; }
  }
  __syncthreads();
  const int r = b * CC + c;
  const int i0 = sidx[0], i1 = sidx[1], i2 = sidx[2];
  const float w0 = lw[0], w1 = lw[1], w2 = lw[2], bias = lb[0];
  for (int s = tid; s < KP / 8; s += 256) {
    const int d0 = s * 8;
    float v[8];
#pragma unroll
    for (int q = 0; q < 8; ++q) v[q] = 0.f;
    if (d0 < 2048) {
      if (i0 >= 0) {
        const float4* p = (const float4*)(imgf + (size_t)i0 * 2048 + d0);
        float4 u0 = p[0], u1 = p[1];
        v[0] += w0 * u0.x; v[1] += w0 * u0.y; v[2] += w0 * u0.z; v[3] += w0 * u0.w;
        v[4] += w0 * u1.x; v[5] += w0 * u1.y; v[6] += w0 * u1.z; v[7] += w0 * u1.w;
      }
      if (i1 >= 0) {
        const float4* p = (const float4*)(imgf + (size_t)i1 * 2048 + d0);
        float4 u0 = p[0], u1 = p[1];
        v[0] += w1 * u0.x; v[1] += w1 * u0.y; v[2] += w1 * u0.z; v[3] += w1 * u0.w;
        v[4] += w1 * u1.x; v[5] += w1 * u1.y; v[6] += w1 * u1.z; v[7] += w1 * u1.w;
      }
      if (i2 >= 0) {
        const float4* p = (const float4*)(imgf + (size_t)i2 * 2048 + d0);
        float4 u0 = p[0], u1 = p[1];
        v[0] += w2 * u0.x; v[1] += w2 * u0.y; v[2] += w2 * u0.z; v[3] += w2 * u0.w;
        v[4] += w2 * u1.x; v[5] += w2 * u1.y; v[6] += w2 * u1.z; v[7] += w2 * u1.w;
      }
#pragma unroll
      for (int q = 0; q < 8; ++q) v[q] += bias;
    } else if (d0 == 2048) {
      if (i0 >= 0) { float4 u = *(const float4*)(bbox + (size_t)i0 * 4);
        v[0] += w0 * u.x; v[1] += w0 * u.y; v[2] += w0 * u.z; v[3] += w0 * u.w; }
      if (i1 >= 0) { float4 u = *(const float4*)(bbox + (size_t)i1 * 4);
        v[0] += w1 * u.x; v[1] += w1 * u.y; v[2] += w1 * u.z; v[3] += w1 * u.w; }
      if (i2 >= 0) { float4 u = *(const float4*)(bbox + (size_t)i2 * 4);
        v[0] += w2 * u.x; v[1] += w2 * u.y; v[2] += w2 * u.z; v[3] += w2 * u.w; }
      v[0] += bias; v[1] += bias; v[2] += bias; v[3] += bias;
    }
    unsigned short o[8] __attribute__((aligned(16)));
#pragma unroll
    for (int q = 0; q < 8; ++q) o[q] = f2bf(v[q]);
    *(uint4*)(xbf + (size_t)r * KP + d0) = *(const uint4*)o;
  }
}

// ---------------------------------------------------------------------------
// KC: support[6400][2048] bf16 = x_bf16 @ gcwT^T.  128x128 tile, BK=64,
// register-prefetch pipeline (global->VGPR during compute, ds_write after
// barrier), XCD-aware tile swizzle (each XCD owns 2 n-columns).
// ---------------------------------------------------------------------------
__global__ __launch_bounds__(256) void k_gemm1(const unsigned short* __restrict__ A,
                                               const unsigned short* __restrict__ Bt,
                                               unsigned short* __restrict__ Cb) {
  __shared__ unsigned short Asm[128 * 64] __attribute__((aligned(16)));
  __shared__ unsigned short Bsm[128 * 64] __attribute__((aligned(16)));
  const int tid  = threadIdx.x;
  const int lane = tid & 63;
  const int w    = tid >> 6;
  // XCD swizzle: v -> (ncol, mrow); consecutive v (round-robin over XCDs)
  // keeps each XCD on 2 n-columns (B slice 1.1 MB < 4 MiB L2).
  const int v    = blockIdx.y * gridDim.x + blockIdx.x;  // 0..799
  const int ncol = (v & 7) * 2 + ((v >> 3) & 1);
  const int mrow = v >> 4;
  const int m0   = mrow * 128;
  const int n0   = ncol * 128;
  const int wm   = (w & 1) * 64;
  const int wn   = (w >> 1) * 64;
  const int srow = lane >> 3;                      // row within 8-row chunk (== m&7)
  const int gk   = (((lane & 7) - srow) & 7) * 8;  // swizzle-inverse k start
  const int quad = lane >> 4;
  const int lrow = lane & 15;
  const int rot  = (lane & 7) * 8;

  // per-thread global base offsets (ushort units) for the 4 A / 4 B chunks
  size_t aoff[4], boff[4];
  int ldsoff[4];
#pragma unroll
  for (int t = 0; t < 4; ++t) {
    const int chunk = t * 4 + w;
    const int row = chunk * 8 + srow;
    aoff[t] = (size_t)(m0 + row) * KP + gk;
    boff[t] = (size_t)(n0 + row) * KP + gk;
    ldsoff[t] = chunk * 512 + lane * 8;
  }

  floatx4 acc[4][4] = {};

  // prologue: stage tile 0 via async16
#pragma unroll
  for (int t = 0; t < 4; ++t) {
    const int chunk = t * 4 + w;
    async16(A  + aoff[t], &Asm[chunk * 512]);
    async16(Bt + boff[t], &Bsm[chunk * 512]);
  }
  __syncthreads();

  uint4 pa[4], pb[4];
  for (int kb = 0; kb < KP / 64; ++kb) {
    const bool more = (kb + 1) < (KP / 64);
    if (more) {
      const int knext = (kb + 1) * 64;
#pragma unroll
      for (int t = 0; t < 4; ++t) {
        pa[t] = *(const uint4*)(A  + aoff[t] + knext);
        pb[t] = *(const uint4*)(Bt + boff[t] + knext);
      }
    }
#pragma unroll
    for (int kp = 0; kp < 2; ++kp) {
      const int koff = (kp * 32 + quad * 8 + rot) & 63;
      short8 af[4], bfr[4];
#pragma unroll
      for (int i = 0; i < 4; ++i)
        af[i]  = *(const short8*)&Asm[(wm + i * 16 + lrow) * 64 + koff];
#pragma unroll
      for (int j = 0; j < 4; ++j)
        bfr[j] = *(const short8*)&Bsm[(wn + j * 16 + lrow) * 64 + koff];
#pragma unroll
      for (int i = 0; i < 4; ++i)
#pragma unroll
        for (int j = 0; j < 4; ++j)
          acc[i][j] = __builtin_amdgcn_mfma_f32_16x16x32_bf16(af[i], bfr[j], acc[i][j], 0, 0, 0);
    }
    __syncthreads();  // all LDS reads of this tile done
    if (more) {
#pragma unroll
      for (int t = 0; t < 4; ++t) {
        *(uint4*)&Asm[ldsoff[t]] = pa[t];
        *(uint4*)&Bsm[ldsoff[t]] = pb[t];
      }
      __syncthreads();  // writes visible
    }
  }
  // epilogue: C/D layout col=lane&15, row=(lane>>4)*4+reg ; store bf16
#pragma unroll
  for (int i = 0; i < 4; ++i)
#pragma unroll
    for (int j = 0; j < 4; ++j) {
      const int col = n0 + wn + j * 16 + lrow;
#pragma unroll
      for (int rr = 0; rr < 4; ++rr) {
        const int row = m0 + wm + i * 16 + quad * 4 + rr;
        Cb[(size_t)row * NOUT + col] = f2bf(acc[i][j][rr]);
      }
    }
}

// ---------------------------------------------------------------------------
// KT: supportB[row=b*100+c][o] bf16 -> supportT[b][o][c pad 128] bf16
// (rows of supportT are 256B-aligned -> async16-stageable in gemm2)
// ---------------------------------------------------------------------------
__global__ __launch_bounds__(256) void k_str(const unsigned short* __restrict__ SB,
                                             unsigned short* __restrict__ ST) {
  __shared__ unsigned short t[32][33];
  const int o0 = blockIdx.x * 32;   // 64
  const int r0 = blockIdx.y * 32;   // 200
  const int tx = threadIdx.x & 31, ty = threadIdx.x >> 5;
#pragma unroll
  for (int i = 0; i < 4; ++i)
    t[ty + i * 8][tx] = SB[(size_t)(r0 + ty + i * 8) * NOUT + o0 + tx];
  __syncthreads();
#pragma unroll
  for (int i = 0; i < 4; ++i) {
    const int o = o0 + ty + i * 8;
    const int r = r0 + tx;
    const int b = r / 100;          // compiler magic-mul
    const int c = r - b * 100;
    ST[((size_t)b * NOUT + o) * 128 + c] = t[tx][ty + i * 8];
  }
}

// ---------------------------------------------------------------------------
// KD: out[b,o] = sum_c g[b,c]*lrelu( sum_n (X[c,n]+adj[b,c,n]) * S[b,n,o] + gc_b[o] )
// bf16 MFMA, S^T staged via async16 from supportT (gemm1-style swizzle, 0-conflict).
// ---------------------------------------------------------------------------
__global__ __launch_bounds__(256) void k_gemm2(const float* __restrict__ X,
                                               const float* __restrict__ adj,
                                               const unsigned short* __restrict__ ST,
                                               const float* __restrict__ gf,
                                               const float* __restrict__ gcb,
                                               float* __restrict__ outp) {
  __shared__ unsigned short A2s[128 * 64] __attribute__((aligned(16)));
  __shared__ unsigned short Ssm[128 * 64] __attribute__((aligned(16)));
  __shared__ float gsm[128];
  __shared__ float red[128 * 9];
  const int tid = threadIdx.x;
  const int o0  = blockIdx.x * 128;
  const int b   = blockIdx.y;
  if (tid < 128) gsm[tid] = (tid < CC) ? gf[b * CC + tid] : 0.f;

  const int lane = tid & 63;
  const int w    = tid >> 6;
  const int srow = lane >> 3;
  const int gk   = (((lane & 7) - srow) & 7) * 8;
  const int quad = lane >> 4;
  const int lrow = lane & 15;
  const int rot  = (lane & 7) * 8;
  const int wm   = (w & 1) * 64;
  const int wn   = (w >> 1) * 64;

  floatx4 acc[4][4] = {};

  for (int kb = 0; kb < 2; ++kb) {
    const int k0 = kb * 64;
    __syncthreads();  // protect LDS reuse across kb
    // S^T staging: 16 chunks of 8 o-rows x 64 k, async16, swizzled
#pragma unroll
    for (int t = 0; t < 4; ++t) {
      const int chunk = t * 4 + w;
      const int orow = chunk * 8 + srow;
      async16(ST + ((size_t)b * NOUT + o0 + orow) * 128 + k0 + gk, &Ssm[chunk * 512]);
    }
    // A2 staging: A2[c][n] = X[c][n]+adj[b][c][n], bf16 x4, same swizzle
    {
      const int ngrp = tid & 15;        // n4 = ngrp*4
      const int cb   = tid >> 4;        // 0..15
      const int n    = k0 + ngrp * 4;
#pragma unroll
      for (int it = 0; it < 8; ++it) {
        const int c = it * 16 + cb;
        unsigned short pk[4] __attribute__((aligned(8))) = {0, 0, 0, 0};
        if (c < CC && n < CC) {         // n multiple of 4 -> n+3 <= 99
          const float4 a4 = *(const float4*)(adj + (size_t)b * (CC * CC) + c * CC + n);
          const float4 x4 = *(const float4*)(X + c * CC + n);
          pk[0] = f2bf(a4.x + x4.x); pk[1] = f2bf(a4.y + x4.y);
          pk[2] = f2bf(a4.z + x4.z); pk[3] = f2bf(a4.w + x4.w);
        }
        *(uint2*)&A2s[c * 64 + ((ngrp * 4 + 8 * (c & 7)) & 63)] = *(const uint2*)pk;
      }
    }
    __syncthreads();
#pragma unroll
    for (int kp = 0; kp < 2; ++kp) {
      const int koff = (kp * 32 + quad * 8 + rot) & 63;
      short8 af[4], bfr[4];
#pragma unroll
      for (int i = 0; i < 4; ++i)
        af[i]  = *(const short8*)&A2s[(wm + i * 16 + lrow) * 64 + koff];
#pragma unroll
      for (int j = 0; j < 4; ++j)
        bfr[j] = *(const short8*)&Ssm[(wn + j * 16 + lrow) * 64 + koff];
#pragma unroll
      for (int i = 0; i < 4; ++i)
#pragma unroll
        for (int j = 0; j < 4; ++j)
          acc[i][j] = __builtin_amdgcn_mfma_f32_16x16x32_bf16(af[i], bfr[j], acc[i][j], 0, 0, 0);
    }
  }
  __syncthreads();

  // epilogue: out_o = sum_c g[c]*lrelu(T[c][o]+bias[o])
  const int slot = (w & 1) * 4 + quad;
#pragma unroll
  for (int j = 0; j < 4; ++j) {
    const int ol = wn + j * 16 + lrow;
    const float bias = gcb[o0 + ol];
    float s = 0.f;
#pragma unroll
    for (int i = 0; i < 4; ++i) {
#pragma unroll
      for (int rr = 0; rr < 4; ++rr) {
        const int c = wm + i * 16 + quad * 4 + rr;
        float t = acc[i][j][rr] + bias;
        t = (t > 0.f) ? t : 0.01f * t;
        s += gsm[c] * t;   // gsm[c]=0 masks c>=100 pad rows
      }
    }
    red[ol * 9 + slot] = s;
  }
  __syncthreads();
  if (tid < 128) {
    float s = 0.f;
#pragma unroll
    for (int t = 0; t < 8; ++t) s += red[tid * 9 + t];
    outp[(size_t)b * NOUT + o0 + tid] = s;
  }
}

// ---------------------------------------------------------------------------
extern "C" void kernel_launch(void* const* d_in, const int* in_sizes, int n_in,
                              void* d_out, int out_size, void* d_ws, size_t ws_size,
                              hipStream_t stream) {
  const float* imgf   = (const float*)d_in[0];
  const float* bbox   = (const float*)d_in[1];
  const float* gfeat  = (const float*)d_in[2];
  const float* adj    = (const float*)d_in[3];
  const float* X      = (const float*)d_in[4];
  const float* lw     = (const float*)d_in[5];
  const float* lb     = (const float*)d_in[6];
  const float* gcw    = (const float*)d_in[7];
  const float* gcb    = (const float*)d_in[8];
  const int*   labels = (const int*)d_in[9];

  char* ws = (char*)d_ws;
  // ws layout (~62 MB total, same as R2):
  //   [0, 27,033,600)            xbf   (dead after gemm1)
  //   [27,033,600, 35,684,352)   gcwT  (dead after gemm1)
  //   [35,684,352, 61,898,752)   supportB
  //   supportT overlays [0, 33,554,432) -- written by k_str AFTER gemm1 retires.
  unsigned short* xbf      = (unsigned short*)(ws);
  unsigned short* gcwT     = (unsigned short*)(ws + 27033600);
  unsigned short* supportB = (unsigned short*)(ws + 35684352);
  unsigned short* supportT = (unsigned short*)(ws);
  float*          outp     = (float*)d_out;

  k_transpose<<<dim3(KP / 32, NOUT / 32), dim3(32, 8), 0, stream>>>(gcw, gcwT);
  k_buildx<<<dim3(CC, BB), dim3(256), 0, stream>>>(imgf, bbox, lw, lb, labels, xbf);
  k_gemm1<<<dim3(16, 50), dim3(256), 0, stream>>>(xbf, gcwT, supportB);
  k_str<<<dim3(NOUT / 32, MR / 32), dim3(256), 0, stream>>>(supportB, supportT);
  k_gemm2<<<dim3(NOUT / 128, BB), dim3(256), 0, stream>>>(X, adj, supportT, gfeat, gcb, outp);
}

// Round 4
// 293.991 us; speedup vs baseline: 1.7147x; 1.7147x over previous
//
#include <hip/hip_runtime.h>
#include <stdint.h>

// Problem constants
#define BB    64
#define CC    100
#define NBPER 150
#define FEAT  2052
#define KP    2112      // FEAT padded to 33*64 for BK=64 MFMA loop
#define NOUT  2048
#define MR    6400      // BB*CC rows of x / support

typedef __attribute__((ext_vector_type(8))) short   short8;
typedef __attribute__((ext_vector_type(4))) float   floatx4;

__device__ __forceinline__ unsigned short f2bf(float f) {
  unsigned int u = __float_as_uint(f);
  u += 0x7FFFu + ((u >> 16) & 1u);   // RNE
  return (unsigned short)(u >> 16);
}

// async global->LDS, 16B per lane. LDS dest is wave-uniform base; HW does base + lane*16.
__device__ __forceinline__ void async16(const void* g, void* l) {
  __builtin_amdgcn_global_load_lds((__attribute__((address_space(1))) void*)(g),
                                   (__attribute__((address_space(3))) void*)(l),
                                   16, 0, 0);
}

// ---------------------------------------------------------------------------
// K0: gc_w [2052][2048] fp32  ->  gcwT [2048][2112] bf16 (K-major, zero-padded)
// ---------------------------------------------------------------------------
__global__ __launch_bounds__(256) void k_transpose(const float* __restrict__ gcw,
                                                   unsigned short* __restrict__ gcwT) {
  __shared__ float tile[32][33];
  const int ko = blockIdx.x;  // 0..65
  const int oo = blockIdx.y;  // 0..63
  const int tx = threadIdx.x, ty = threadIdx.y;
#pragma unroll
  for (int i = 0; i < 4; ++i) {
    const int k = ko * 32 + ty + i * 8;
    const int o = oo * 32 + tx;
    tile[ty + i * 8][tx] = (k < FEAT) ? gcw[(size_t)k * NOUT + o] : 0.f;
  }
  __syncthreads();
#pragma unroll
  for (int i = 0; i < 4; ++i) {
    const int o = oo * 32 + ty + i * 8;
    const int k = ko * 32 + tx;
    gcwT[(size_t)o * KP + k] = f2bf(tile[tx][ty + i * 8]);
  }
}

// ---------------------------------------------------------------------------
// KB: bucket (fused) + x[b,c,d] = lin_b + sum_slot lin_w[slot]*full[box][d] -> bf16
// ---------------------------------------------------------------------------
__global__ __launch_bounds__(256) void k_buildx(const float* __restrict__ imgf,
                                                const float* __restrict__ bbox,
                                                const float* __restrict__ lw,
                                                const float* __restrict__ lb,
                                                const int* __restrict__ labels,
                                                unsigned short* __restrict__ xbf) {
  __shared__ int lab[NBPER];
  __shared__ int sidx[3];
  const int c = blockIdx.x, b = blockIdx.y;
  const int tid = threadIdx.x;
  if (tid < NBPER) lab[tid] = labels[b * NBPER + tid];
  __syncthreads();
  if (tid == 0) {
    int cnt = 0; sidx[0] = -1; sidx[1] = -1; sidx[2] = -1;
    for (int i = 0; i < NBPER; ++i)
      if (lab[i] == c + 1 && cnt < 3) { sidx[cnt] = b * NBPER + i; ++cnt; }
  }
  __syncthreads();
  const int r = b * CC + c;
  const int i0 = sidx[0], i1 = sidx[1], i2 = sidx[2];
  const float w0 = lw[0], w1 = lw[1], w2 = lw[2], bias = lb[0];
  for (int s = tid; s < KP / 8; s += 256) {
    const int d0 = s * 8;
    float v[8];
#pragma unroll
    for (int q = 0; q < 8; ++q) v[q] = 0.f;
    if (d0 < 2048) {
      if (i0 >= 0) {
        const float4* p = (const float4*)(imgf + (size_t)i0 * 2048 + d0);
        float4 u0 = p[0], u1 = p[1];
        v[0] += w0 * u0.x; v[1] += w0 * u0.y; v[2] += w0 * u0.z; v[3] += w0 * u0.w;
        v[4] += w0 * u1.x; v[5] += w0 * u1.y; v[6] += w0 * u1.z; v[7] += w0 * u1.w;
      }
      if (i1 >= 0) {
        const float4* p = (const float4*)(imgf + (size_t)i1 * 2048 + d0);
        float4 u0 = p[0], u1 = p[1];
        v[0] += w1 * u0.x; v[1] += w1 * u0.y; v[2] += w1 * u0.z; v[3] += w1 * u0.w;
        v[4] += w1 * u1.x; v[5] += w1 * u1.y; v[6] += w1 * u1.z; v[7] += w1 * u1.w;
      }
      if (i2 >= 0) {
        const float4* p = (const float4*)(imgf + (size_t)i2 * 2048 + d0);
        float4 u0 = p[0], u1 = p[1];
        v[0] += w2 * u0.x; v[1] += w2 * u0.y; v[2] += w2 * u0.z; v[3] += w2 * u0.w;
        v[4] += w2 * u1.x; v[5] += w2 * u1.y; v[6] += w2 * u1.z; v[7] += w2 * u1.w;
      }
#pragma unroll
      for (int q = 0; q < 8; ++q) v[q] += bias;
    } else if (d0 == 2048) {
      if (i0 >= 0) { float4 u = *(const float4*)(bbox + (size_t)i0 * 4);
        v[0] += w0 * u.x; v[1] += w0 * u.y; v[2] += w0 * u.z; v[3] += w0 * u.w; }
      if (i1 >= 0) { float4 u = *(const float4*)(bbox + (size_t)i1 * 4);
        v[0] += w1 * u.x; v[1] += w1 * u.y; v[2] += w1 * u.z; v[3] += w1 * u.w; }
      if (i2 >= 0) { float4 u = *(const float4*)(bbox + (size_t)i2 * 4);
        v[0] += w2 * u.x; v[1] += w2 * u.y; v[2] += w2 * u.z; v[3] += w2 * u.w; }
      v[0] += bias; v[1] += bias; v[2] += bias; v[3] += bias;
    }
    unsigned short o[8] __attribute__((aligned(16)));
#pragma unroll
    for (int q = 0; q < 8; ++q) o[q] = f2bf(v[q]);
    *(uint4*)(xbf + (size_t)r * KP + d0) = *(const uint4*)o;
  }
}

// ---------------------------------------------------------------------------
// KC: support = x_bf16 @ gcwT^T, written DIRECTLY transposed into
// supportT[b][o][c pad 128] bf16. 128x128 tile, BK=64, async16 staging
// (R2-proven 2-barrier K-loop; NO register prefetch -- that spilled in R3),
// XCD-aware tile swizzle, LDS-transpose epilogue.
// ---------------------------------------------------------------------------
__global__ __launch_bounds__(256) void k_gemm1(const unsigned short* __restrict__ A,
                                               const unsigned short* __restrict__ Bt,
                                               unsigned short* __restrict__ ST) {
  __shared__ unsigned short shbuf[128 * 132] __attribute__((aligned(16)));  // 33.8 KB
  unsigned short* Asm = shbuf;          // staging: 8192 ushorts
  unsigned short* Bsm = shbuf + 8192;   //          8192 ushorts
  const int tid  = threadIdx.x;
  const int lane = tid & 63;
  const int w    = tid >> 6;
  // XCD swizzle: consecutive v round-robin over XCDs; each XCD owns 2 n-cols.
  const int v    = blockIdx.y * gridDim.x + blockIdx.x;  // 0..799
  const int ncol = (v & 7) * 2 + ((v >> 3) & 1);
  const int mrow = v >> 4;
  const int m0   = mrow * 128;
  const int n0   = ncol * 128;
  const int wm   = (w & 1) * 64;
  const int wn   = (w >> 1) * 64;
  const int srow = lane >> 3;                      // row within 8-row chunk (== m&7)
  const int gk   = (((lane & 7) - srow) & 7) * 8;  // swizzle-inverse k start
  const int quad = lane >> 4;
  const int lrow = lane & 15;
  const int rot  = (lane & 7) * 8;

  floatx4 acc[4][4] = {};

  for (int kb = 0; kb < KP / 64; ++kb) {
    const int k0 = kb * 64;
#pragma unroll
    for (int t = 0; t < 4; ++t) {
      const int chunk = t * 4 + w;
      const int row = chunk * 8 + srow;
      async16(A  + (size_t)(m0 + row) * KP + (k0 + gk), &Asm[chunk * 512]);
      async16(Bt + (size_t)(n0 + row) * KP + (k0 + gk), &Bsm[chunk * 512]);
    }
    __syncthreads();  // drains vmcnt + barrier
#pragma unroll
    for (int kp = 0; kp < 2; ++kp) {
      const int koff = (kp * 32 + quad * 8 + rot) & 63;
      short8 af[4], bfr[4];
#pragma unroll
      for (int i = 0; i < 4; ++i)
        af[i]  = *(const short8*)&Asm[(wm + i * 16 + lrow) * 64 + koff];
#pragma unroll
      for (int j = 0; j < 4; ++j)
        bfr[j] = *(const short8*)&Bsm[(wn + j * 16 + lrow) * 64 + koff];
#pragma unroll
      for (int i = 0; i < 4; ++i)
#pragma unroll
        for (int j = 0; j < 4; ++j)
          acc[i][j] = __builtin_amdgcn_mfma_f32_16x16x32_bf16(af[i], bfr[j], acc[i][j], 0, 0, 0);
    }
    __syncthreads();
  }

  // epilogue: acc(row=m_local, col=o_local) -> LDS T[o][m] (stride 132), then
  // coalesced uint stores into ST[b][n0+o][c] (c,c+1 never straddle b: m0 even).
#pragma unroll
  for (int j = 0; j < 4; ++j) {
    const int ol = wn + j * 16 + lrow;
#pragma unroll
    for (int i = 0; i < 4; ++i) {
#pragma unroll
      for (int rr = 0; rr < 4; ++rr) {
        const int ml = wm + i * 16 + quad * 4 + rr;
        shbuf[ol * 132 + ml] = f2bf(acc[i][j][rr]);
      }
    }
  }
  __syncthreads();
#pragma unroll
  for (int it = 0; it < 32; ++it) {
    const int idx = it * 256 + tid;
    const int o = idx >> 6;          // 0..127
    const int cp = idx & 63;         // c-pair
    const int m = 2 * cp;
    const int r = m0 + m;
    const int b = r / 100;           // magic-mul
    const int c = r - b * 100;       // even; (c,c+1) same b
    const unsigned int val = *(const unsigned int*)&shbuf[o * 132 + m];
    *(unsigned int*)&ST[((size_t)b * NOUT + n0 + o) * 128 + c] = val;
  }
}

// ---------------------------------------------------------------------------
// KD: out[b,o] = sum_c g[b,c]*lrelu( sum_n (X[c,n]+adj[b,c,n]) * S[b,n,o] + gc_b[o] )
// bf16 MFMA, S^T staged via async16 from supportT (0-conflict swizzle).
// ---------------------------------------------------------------------------
__global__ __launch_bounds__(256) void k_gemm2(const float* __restrict__ X,
                                               const float* __restrict__ adj,
                                               const unsigned short* __restrict__ ST,
                                               const float* __restrict__ gf,
                                               const float* __restrict__ gcb,
                                               float* __restrict__ outp) {
  __shared__ unsigned short A2s[128 * 64] __attribute__((aligned(16)));
  __shared__ unsigned short Ssm[128 * 64] __attribute__((aligned(16)));
  __shared__ float gsm[128];
  __shared__ float red[128 * 9];
  const int tid = threadIdx.x;
  const int o0  = blockIdx.x * 128;
  const int b   = blockIdx.y;
  if (tid < 128) gsm[tid] = (tid < CC) ? gf[b * CC + tid] : 0.f;

  const int lane = tid & 63;
  const int w    = tid >> 6;
  const int srow = lane >> 3;
  const int gk   = (((lane & 7) - srow) & 7) * 8;
  const int quad = lane >> 4;
  const int lrow = lane & 15;
  const int rot  = (lane & 7) * 8;
  const int wm   = (w & 1) * 64;
  const int wn   = (w >> 1) * 64;

  floatx4 acc[4][4] = {};

  for (int kb = 0; kb < 2; ++kb) {
    const int k0 = kb * 64;
    __syncthreads();  // protect LDS reuse across kb
#pragma unroll
    for (int t = 0; t < 4; ++t) {
      const int chunk = t * 4 + w;
      const int orow = chunk * 8 + srow;
      async16(ST + ((size_t)b * NOUT + o0 + orow) * 128 + k0 + gk, &Ssm[chunk * 512]);
    }
    // A2 staging: A2[c][n] = X[c][n]+adj[b][c][n], bf16 x4, same swizzle
    {
      const int ngrp = tid & 15;
      const int cb   = tid >> 4;
      const int n    = k0 + ngrp * 4;
#pragma unroll
      for (int it = 0; it < 8; ++it) {
        const int c = it * 16 + cb;
        unsigned short pk[4] __attribute__((aligned(8))) = {0, 0, 0, 0};
        if (c < CC && n < CC) {
          const float4 a4 = *(const float4*)(adj + (size_t)b * (CC * CC) + c * CC + n);
          const float4 x4 = *(const float4*)(X + c * CC + n);
          pk[0] = f2bf(a4.x + x4.x); pk[1] = f2bf(a4.y + x4.y);
          pk[2] = f2bf(a4.z + x4.z); pk[3] = f2bf(a4.w + x4.w);
        }
        *(uint2*)&A2s[c * 64 + ((ngrp * 4 + 8 * (c & 7)) & 63)] = *(const uint2*)pk;
      }
    }
    __syncthreads();
#pragma unroll
    for (int kp = 0; kp < 2; ++kp) {
      const int koff = (kp * 32 + quad * 8 + rot) & 63;
      short8 af[4], bfr[4];
#pragma unroll
      for (int i = 0; i < 4; ++i)
        af[i]  = *(const short8*)&A2s[(wm + i * 16 + lrow) * 64 + koff];
#pragma unroll
      for (int j = 0; j < 4; ++j)
        bfr[j] = *(const short8*)&Ssm[(wn + j * 16 + lrow) * 64 + koff];
#pragma unroll
      for (int i = 0; i < 4; ++i)
#pragma unroll
        for (int j = 0; j < 4; ++j)
          acc[i][j] = __builtin_amdgcn_mfma_f32_16x16x32_bf16(af[i], bfr[j], acc[i][j], 0, 0, 0);
    }
  }
  __syncthreads();

  const int slot = (w & 1) * 4 + quad;
#pragma unroll
  for (int j = 0; j < 4; ++j) {
    const int ol = wn + j * 16 + lrow;
    const float bias = gcb[o0 + ol];
    float s = 0.f;
#pragma unroll
    for (int i = 0; i < 4; ++i) {
#pragma unroll
      for (int rr = 0; rr < 4; ++rr) {
        const int c = wm + i * 16 + quad * 4 + rr;
        float t = acc[i][j][rr] + bias;
        t = (t > 0.f) ? t : 0.01f * t;
        s += gsm[c] * t;   // gsm[c]=0 masks c>=100 pad rows
      }
    }
    red[ol * 9 + slot] = s;
  }
  __syncthreads();
  if (tid < 128) {
    float s = 0.f;
#pragma unroll
    for (int t = 0; t < 8; ++t) s += red[tid * 9 + t];
    outp[(size_t)b * NOUT + o0 + tid] = s;
  }
}

// ---------------------------------------------------------------------------
extern "C" void kernel_launch(void* const* d_in, const int* in_sizes, int n_in,
                              void* d_out, int out_size, void* d_ws, size_t ws_size,
                              hipStream_t stream) {
  const float* imgf   = (const float*)d_in[0];
  const float* bbox   = (const float*)d_in[1];
  const float* gfeat  = (const float*)d_in[2];
  const float* adj    = (const float*)d_in[3];
  const float* X      = (const float*)d_in[4];
  const float* lw     = (const float*)d_in[5];
  const float* lb     = (const float*)d_in[6];
  const float* gcw    = (const float*)d_in[7];
  const float* gcb    = (const float*)d_in[8];
  const int*   labels = (const int*)d_in[9];

  char* ws = (char*)d_ws;
  // ws layout (~69.2 MB total; ST must NOT overlay xbf -- gemm1 reads xbf
  // while writing ST):
  //   [0, 27,033,600)             xbf
  //   [27,033,600, 35,684,352)    gcwT
  //   [35,684,352, 69,238,784)    supportT [64][2048][128] bf16
  unsigned short* xbf      = (unsigned short*)(ws);
  unsigned short* gcwT     = (unsigned short*)(ws + 27033600);
  unsigned short* supportT = (unsigned short*)(ws + 35684352);
  float*          outp     = (float*)d_out;

  k_transpose<<<dim3(KP / 32, NOUT / 32), dim3(32, 8), 0, stream>>>(gcw, gcwT);
  k_buildx<<<dim3(CC, BB), dim3(256), 0, stream>>>(imgf, bbox, lw, lb, labels, xbf);
  k_gemm1<<<dim3(16, 50), dim3(256), 0, stream>>>(xbf, gcwT, supportT);
  k_gemm2<<<dim3(NOUT / 128, BB), dim3(256), 0, stream>>>(X, adj, supportT, gfeat, gcb, outp);
}